// Round 1
// baseline (519.652 us; speedup 1.0000x reference)
//
#include <hip/hip_runtime.h>
#include <math.h>

// Problem constants (match reference)
#define BATCH   4096
#define FEAT    64
#define EMB     32
#define MODELS  512
#define SEQ     128
#define KDIM    (FEAT * EMB)   // 2048

// Tile config
#define BM 64
#define BN 64
#define BK 32                  // one feature (32 emb floats) per K-tile

__global__ __launch_bounds__(256, 2)
void fused_emb_gemm_pe(const int*   __restrict__ tokens,   // [BATCH][FEAT]
                       const float* __restrict__ emb,      // [VOCAB][EMB]
                       const float* __restrict__ W,        // [KDIM][MODELS]
                       const float* __restrict__ bias,     // [MODELS]
                       float*       __restrict__ out)      // [BATCH][SEQ][MODELS]
{
    __shared__ float As[BK][BM];        // A tile, transposed: As[k][row]  (8 KB)
    __shared__ float Bs[BK][BN];        // W tile                      (8 KB)
    __shared__ float peS[SEQ][BN];      // positional-encoding slice  (32 KB)

    const int tid  = threadIdx.x;
    const int bn   = blockIdx.x * BN;   // model-column base
    const int brow = blockIdx.y * BM;   // batch-row base

    // ---- positional encoding tile for this block's 64 columns ----
    // pe[s][m] = sin(s * rate(m)) if m even else cos(s * rate(m))
    // rate(m)  = 10000^(-2*floor(m/2)/512)
    for (int idx = tid; idx < SEQ * BN; idx += 256) {
        const int s  = idx >> 6;        // /64
        const int ml = idx & 63;
        const int m  = bn + ml;
        const float expo = (float)(2 * (m >> 1)) * (1.0f / 512.0f);
        const float rate = expf(-expo * 9.210340371976184f);  // ln(10000)
        const float ang  = (float)s * rate;
        peS[s][ml] = (m & 1) ? cosf(ang) : sinf(ang);
    }

    // ---- GEMM: x[brow..+64][bn..+64] = (gather * sqrt(512)) @ W ----
    float acc[4][4] = {};
    const int tx = tid & 15;            // 0..15 -> column group (4 cols)
    const int ty = tid >> 4;            // 0..15 -> row group (4 rows)

    // A loader: 4 threads per row, each loads 8 contiguous emb floats
    const int lr = tid >> 2;            // row within tile, 0..63
    const int lj = tid & 3;             // 0..3 -> floats [lj*8, lj*8+8)
    // B loader: thread -> (k = tid>>4 and +16, col chunk = (tid&15)*4)
    const int bk = tid >> 4;            // 0..15
    const int bc = (tid & 15) * 4;      // 0..60

    const float scale = 22.62741699796952f;   // sqrt(512)

    for (int kt = 0; kt < FEAT; ++kt) {
        __syncthreads();   // previous tile fully consumed

        // gather A: row lr uses emb_table[tokens[brow+lr][kt]]
        {
            const int tok = tokens[(brow + lr) * FEAT + kt];
            const float* erow = emb + (size_t)tok * EMB + lj * 8;
            const float4 a0 = *(const float4*)(erow);
            const float4 a1 = *(const float4*)(erow + 4);
            const int k0 = lj * 8;
            As[k0 + 0][lr] = a0.x * scale;
            As[k0 + 1][lr] = a0.y * scale;
            As[k0 + 2][lr] = a0.z * scale;
            As[k0 + 3][lr] = a0.w * scale;
            As[k0 + 4][lr] = a1.x * scale;
            As[k0 + 5][lr] = a1.y * scale;
            As[k0 + 6][lr] = a1.z * scale;
            As[k0 + 7][lr] = a1.w * scale;
        }
        // load W tile: rows kt*32 .. +32, cols bn .. +64
        {
            const float* w0 = W + (size_t)(kt * 32 + bk) * MODELS + bn + bc;
            const float* w1 = W + (size_t)(kt * 32 + bk + 16) * MODELS + bn + bc;
            *(float4*)&Bs[bk][bc]      = *(const float4*)w0;
            *(float4*)&Bs[bk + 16][bc] = *(const float4*)w1;
        }
        __syncthreads();

        #pragma unroll
        for (int k = 0; k < BK; ++k) {
            const float4 a = *(const float4*)&As[k][ty * 4];
            const float4 b = *(const float4*)&Bs[k][tx * 4];
            acc[0][0] += a.x * b.x; acc[0][1] += a.x * b.y; acc[0][2] += a.x * b.z; acc[0][3] += a.x * b.w;
            acc[1][0] += a.y * b.x; acc[1][1] += a.y * b.y; acc[1][2] += a.y * b.z; acc[1][3] += a.y * b.w;
            acc[2][0] += a.z * b.x; acc[2][1] += a.z * b.y; acc[2][2] += a.z * b.z; acc[2][3] += a.z * b.w;
            acc[3][0] += a.w * b.x; acc[3][1] += a.w * b.y; acc[3][2] += a.w * b.z; acc[3][3] += a.w * b.w;
        }
    }

    // ---- bias ----
    {
        const float4 bv = *(const float4*)(bias + bn + tx * 4);
        #pragma unroll
        for (int i = 0; i < 4; ++i) {
            acc[i][0] += bv.x; acc[i][1] += bv.y; acc[i][2] += bv.z; acc[i][3] += bv.w;
        }
    }

    // ---- broadcast over seq + pe add, streamed float4 stores ----
    size_t rowbase[4];
    #pragma unroll
    for (int i = 0; i < 4; ++i)
        rowbase[i] = ((size_t)(brow + ty * 4 + i) * SEQ) * MODELS + bn + tx * 4;

    #pragma unroll 4
    for (int s = 0; s < SEQ; ++s) {
        const float4 pv = *(const float4*)&peS[s][tx * 4];
        const size_t soff = (size_t)s * MODELS;
        #pragma unroll
        for (int i = 0; i < 4; ++i) {
            float4 o;
            o.x = acc[i][0] + pv.x;
            o.y = acc[i][1] + pv.y;
            o.z = acc[i][2] + pv.z;
            o.w = acc[i][3] + pv.w;
            *(float4*)(out + rowbase[i] + soff) = o;
        }
    }
}

extern "C" void kernel_launch(void* const* d_in, const int* in_sizes, int n_in,
                              void* d_out, int out_size, void* d_ws, size_t ws_size,
                              hipStream_t stream) {
    const int*   tokens = (const int*)d_in[0];
    const float* emb    = (const float*)d_in[1];
    const float* W      = (const float*)d_in[2];
    const float* bias   = (const float*)d_in[3];
    float*       out    = (float*)d_out;

    const int batch = in_sizes[0] / FEAT;   // 4096
    dim3 grid(MODELS / BN, batch / BM);     // (8, 64)
    dim3 block(256);
    fused_emb_gemm_pe<<<grid, block, 0, stream>>>(tokens, emb, W, bias, out);
}

// Round 2
// 301.817 us; speedup vs baseline: 1.7217x; 1.7217x over previous
//
#include <hip/hip_runtime.h>
#include <math.h>

#define BATCH   4096
#define FEAT    64
#define EMB     32
#define MODELS  512
#define SEQ     128
#define KDIM    (FEAT * EMB)   // 2048

#define SQRT_MODELS 22.62741699796952f
#define LN10000     9.210340371976184f

typedef __attribute__((ext_vector_type(4))) float    f32x4;
typedef __attribute__((ext_vector_type(8))) short    bf16x8;
typedef __attribute__((ext_vector_type(4))) unsigned int u32x4;

// ws layout
#define WT_BYTES ((size_t)MODELS * KDIM * 2)          // 2 MB  (bf16 W^T, pre-scaled)
#define PE_BYTES ((size_t)SEQ * MODELS * 4)           // 256 KB (pe + bias)
#define X_BYTES  ((size_t)BATCH * MODELS * 4)         // 8 MB
#define WS_NEEDED (WT_BYTES + PE_BYTES + X_BYTES)

__device__ inline unsigned short bf16_rne(float f) {
    unsigned int b = __builtin_bit_cast(unsigned int, f);
    return (unsigned short)((b + 0x7FFFu + ((b >> 16) & 1u)) >> 16);
}

// ---------------- P1: Wt[n][k] = W[k][n] * sqrt(512), bf16 ----------------
__global__ __launch_bounds__(256)
void prep_wt(const float* __restrict__ W, unsigned short* __restrict__ Wt) {
    __shared__ float t[32][33];
    const int k0 = blockIdx.x * 32;          // 64 blocks
    const int n0 = blockIdx.y * 32;          // 16 blocks
    const int tx = threadIdx.x;              // 0..31
    const int ty = threadIdx.y;              // 0..7
    #pragma unroll
    for (int i = 0; i < 4; ++i) {
        const int kk = ty + i * 8;
        t[kk][tx] = W[(size_t)(k0 + kk) * MODELS + n0 + tx] * SQRT_MODELS;
    }
    __syncthreads();
    #pragma unroll
    for (int i = 0; i < 4; ++i) {
        const int nn = ty + i * 8;
        Wt[(size_t)(n0 + nn) * KDIM + k0 + tx] = bf16_rne(t[tx][nn]);
    }
}

// ---------------- P2: pe[s][m] (+ bias[m] folded in) ----------------
__global__ __launch_bounds__(256)
void prep_pe(const float* __restrict__ bias, float* __restrict__ pe) {
    const int idx = blockIdx.x * 256 + threadIdx.x;   // 256 blocks -> 65536
    const int s = idx >> 9;
    const int m = idx & (MODELS - 1);
    const float rate = expf(-LN10000 * (float)(2 * (m >> 1)) * (1.0f / 512.0f));
    const float ang  = (float)s * rate;
    pe[idx] = ((m & 1) ? cosf(ang) : sinf(ang)) + bias[m];
}

// ---------------- A: x = gather(emb) @ (s*W) + 0, bf16 MFMA, no LDS ----------------
// block: 256 thr = 4 waves. Block tile M=16, N=256 (wave: 16x64).
__global__ __launch_bounds__(256)
void gemm_mfma(const int* __restrict__ tokens, const float* __restrict__ emb,
               const unsigned short* __restrict__ Wt, float* __restrict__ x) {
    const int tid  = threadIdx.x;
    const int wave = tid >> 6;
    const int lane = tid & 63;
    const int ln   = lane & 15;              // A row index AND D col index
    const int kg   = lane >> 4;              // 0..3 (k-group of 8)

    const int m_base = blockIdx.y * 16;
    const int n_base = blockIdx.x * 256 + wave * 64;

    const int* trow = tokens + (size_t)(m_base + ln) * FEAT;

    // B row pointers for this lane's 4 n-fragments
    const unsigned short* bptr[4];
    #pragma unroll
    for (int nf = 0; nf < 4; ++nf)
        bptr[nf] = Wt + (size_t)(n_base + nf * 16 + ln) * KDIM + kg * 8;

    f32x4 acc[4] = {f32x4{0,0,0,0}, f32x4{0,0,0,0}, f32x4{0,0,0,0}, f32x4{0,0,0,0}};

    for (int f4 = 0; f4 < FEAT; f4 += 4) {
        const int4 tok4 = *(const int4*)(trow + f4);
        const int toks[4] = {tok4.x, tok4.y, tok4.z, tok4.w};
        #pragma unroll
        for (int j = 0; j < 4; ++j) {
            const int f = f4 + j;
            const float* ea = emb + (size_t)toks[j] * EMB + kg * 8;
            const f32x4 a0 = *(const f32x4*)ea;
            const f32x4 a1 = *(const f32x4*)(ea + 4);
            unsigned int q0, q1, q2, q3;
            asm("v_cvt_pk_bf16_f32 %0, %1, %2" : "=v"(q0) : "v"(a0.x), "v"(a0.y));
            asm("v_cvt_pk_bf16_f32 %0, %1, %2" : "=v"(q1) : "v"(a0.z), "v"(a0.w));
            asm("v_cvt_pk_bf16_f32 %0, %1, %2" : "=v"(q2) : "v"(a1.x), "v"(a1.y));
            asm("v_cvt_pk_bf16_f32 %0, %1, %2" : "=v"(q3) : "v"(a1.z), "v"(a1.w));
            const u32x4 pk = {q0, q1, q2, q3};
            const bf16x8 afrag = __builtin_bit_cast(bf16x8, pk);
            #pragma unroll
            for (int nf = 0; nf < 4; ++nf) {
                const bf16x8 bfrag = *(const bf16x8*)(bptr[nf] + (size_t)f * EMB);
                acc[nf] = __builtin_amdgcn_mfma_f32_16x16x32_bf16(afrag, bfrag, acc[nf], 0, 0, 0);
            }
        }
    }

    // D mapping (verified): col = lane&15, row = (lane>>4)*4 + reg
    #pragma unroll
    for (int nf = 0; nf < 4; ++nf) {
        #pragma unroll
        for (int q = 0; q < 4; ++q) {
            const int r = kg * 4 + q;
            x[(size_t)(m_base + r) * MODELS + n_base + nf * 16 + ln] = acc[nf][q];
        }
    }
}

// ---------------- B: out[b][s][m] = x[b][m] + pe[s][m] ----------------
__global__ __launch_bounds__(256)
void bcast_pe(const float* __restrict__ x, const float* __restrict__ pe,
              float* __restrict__ out) {
    const int tid = threadIdx.x;
    const int m4  = tid & 127;                       // float4 index over 512 cols
    const int b   = blockIdx.x * 2 + (tid >> 7);
    const f32x4 xv = *(const f32x4*)(x + (size_t)b * MODELS + m4 * 4);
    const f32x4* pev = (const f32x4*)pe;
    float* ob = out + (size_t)b * SEQ * MODELS + m4 * 4;
    #pragma unroll 4
    for (int s = 0; s < SEQ; ++s) {
        const f32x4 p = pev[s * 128 + m4];
        *(f32x4*)(ob + (size_t)s * MODELS) = xv + p;
    }
}

// ---------------- fallback: the verified fused kernel (round-1) ----------------
#define BM 64
#define BN 64
#define BK 32
__global__ __launch_bounds__(256, 2)
void fused_emb_gemm_pe(const int* __restrict__ tokens, const float* __restrict__ emb,
                       const float* __restrict__ W, const float* __restrict__ bias,
                       float* __restrict__ out) {
    __shared__ float As[BK][BM];
    __shared__ float Bs[BK][BN];
    __shared__ float peS[SEQ][BN];
    const int tid  = threadIdx.x;
    const int bn   = blockIdx.x * BN;
    const int brow = blockIdx.y * BM;
    for (int idx = tid; idx < SEQ * BN; idx += 256) {
        const int s  = idx >> 6;
        const int ml = idx & 63;
        const int m  = bn + ml;
        const float rate = expf(-LN10000 * (float)(2 * (m >> 1)) * (1.0f / 512.0f));
        const float ang  = (float)s * rate;
        peS[s][ml] = (m & 1) ? cosf(ang) : sinf(ang);
    }
    float acc[4][4] = {};
    const int tx = tid & 15;
    const int ty = tid >> 4;
    const int lr = tid >> 2;
    const int lj = tid & 3;
    const int bk = tid >> 4;
    const int bc = (tid & 15) * 4;
    for (int kt = 0; kt < FEAT; ++kt) {
        __syncthreads();
        {
            const int tok = tokens[(brow + lr) * FEAT + kt];
            const float* erow = emb + (size_t)tok * EMB + lj * 8;
            const float4 a0 = *(const float4*)(erow);
            const float4 a1 = *(const float4*)(erow + 4);
            const int k0 = lj * 8;
            As[k0 + 0][lr] = a0.x * SQRT_MODELS; As[k0 + 1][lr] = a0.y * SQRT_MODELS;
            As[k0 + 2][lr] = a0.z * SQRT_MODELS; As[k0 + 3][lr] = a0.w * SQRT_MODELS;
            As[k0 + 4][lr] = a1.x * SQRT_MODELS; As[k0 + 5][lr] = a1.y * SQRT_MODELS;
            As[k0 + 6][lr] = a1.z * SQRT_MODELS; As[k0 + 7][lr] = a1.w * SQRT_MODELS;
        }
        {
            const float* w0 = W + (size_t)(kt * 32 + bk) * MODELS + bn + bc;
            const float* w1 = W + (size_t)(kt * 32 + bk + 16) * MODELS + bn + bc;
            *(float4*)&Bs[bk][bc]      = *(const float4*)w0;
            *(float4*)&Bs[bk + 16][bc] = *(const float4*)w1;
        }
        __syncthreads();
        #pragma unroll
        for (int k = 0; k < BK; ++k) {
            const float4 a = *(const float4*)&As[k][ty * 4];
            const float4 b = *(const float4*)&Bs[k][tx * 4];
            acc[0][0] += a.x * b.x; acc[0][1] += a.x * b.y; acc[0][2] += a.x * b.z; acc[0][3] += a.x * b.w;
            acc[1][0] += a.y * b.x; acc[1][1] += a.y * b.y; acc[1][2] += a.y * b.z; acc[1][3] += a.y * b.w;
            acc[2][0] += a.z * b.x; acc[2][1] += a.z * b.y; acc[2][2] += a.z * b.z; acc[2][3] += a.z * b.w;
            acc[3][0] += a.w * b.x; acc[3][1] += a.w * b.y; acc[3][2] += a.w * b.z; acc[3][3] += a.w * b.w;
        }
    }
    {
        const float4 bv = *(const float4*)(bias + bn + tx * 4);
        #pragma unroll
        for (int i = 0; i < 4; ++i) {
            acc[i][0] += bv.x; acc[i][1] += bv.y; acc[i][2] += bv.z; acc[i][3] += bv.w;
        }
    }
    size_t rowbase[4];
    #pragma unroll
    for (int i = 0; i < 4; ++i)
        rowbase[i] = ((size_t)(brow + ty * 4 + i) * SEQ) * MODELS + bn + tx * 4;
    #pragma unroll 4
    for (int s = 0; s < SEQ; ++s) {
        const float4 pv = *(const float4*)&peS[s][tx * 4];
        const size_t soff = (size_t)s * MODELS;
        #pragma unroll
        for (int i = 0; i < 4; ++i) {
            float4 o;
            o.x = acc[i][0] + pv.x; o.y = acc[i][1] + pv.y;
            o.z = acc[i][2] + pv.z; o.w = acc[i][3] + pv.w;
            *(float4*)(out + rowbase[i] + soff) = o;
        }
    }
}

extern "C" void kernel_launch(void* const* d_in, const int* in_sizes, int n_in,
                              void* d_out, int out_size, void* d_ws, size_t ws_size,
                              hipStream_t stream) {
    const int*   tokens = (const int*)d_in[0];
    const float* emb    = (const float*)d_in[1];
    const float* W      = (const float*)d_in[2];
    const float* bias   = (const float*)d_in[3];
    float*       out    = (float*)d_out;

    if (ws_size >= WS_NEEDED) {
        char* w = (char*)d_ws;
        unsigned short* Wt = (unsigned short*)w;
        float* pe = (float*)(w + WT_BYTES);
        float* x  = (float*)(w + WT_BYTES + PE_BYTES);

        prep_wt<<<dim3(KDIM / 32, MODELS / 32), dim3(32, 8), 0, stream>>>(W, Wt);
        prep_pe<<<dim3(SEQ * MODELS / 256), dim3(256), 0, stream>>>(bias, pe);
        gemm_mfma<<<dim3(MODELS / 256, BATCH / 16), dim3(256), 0, stream>>>(tokens, emb, Wt, x);
        bcast_pe<<<dim3(BATCH / 2), dim3(256), 0, stream>>>(x, pe, out);
    } else {
        fused_emb_gemm_pe<<<dim3(MODELS / BN, BATCH / BM), dim3(256), 0, stream>>>(
            tokens, emb, W, bias, out);
    }
}